// Round 6
// baseline (187.644 us; speedup 1.0000x reference)
//
#include <hip/hip_runtime.h>

#define NA 16
#define DD 513
#define ALPHA 0.1f
#define EPSV 1e-7f
#define RPW 8             // rows per wave, processed in pairs
#define GRID 4096         // 4096 blocks * 4 waves * 8 rows = 131072

typedef __fp16 h2 __attribute__((ext_vector_type(2)));
typedef unsigned int u32;

union H2U { h2 h; u32 u; };
union FU  { float f; u32 u; };

static __device__ __forceinline__ u32 pkrtz(float lo, float hi) {
    H2U t; t.h = __builtin_amdgcn_cvt_pkrtz(lo, hi); return t.u;
}
static __device__ __forceinline__ h2 asH2(u32 w) { H2U t; t.u = w; return t.h; }

static __device__ __forceinline__ float fdot2(u32 a, u32 b, float c) {
    return __builtin_amdgcn_fdot2(asH2(a), asH2(b), c, false);
}

// two-row interleaved butterfly reduce: 64 lanes x 16 vals -> per-lane sum
// for anchor aidx(lane) = bitrev4(lane & 15)
#define RSTEP2(m, half)                                             \
    _Pragma("unroll")                                               \
    for (int i = 0; i < half; ++i) {                                \
        const bool up = (lane & m) != 0;                            \
        float s0 = up ? v0[i] : v0[half + i];                       \
        float k0 = up ? v0[half + i] : v0[i];                       \
        float s1 = up ? v1[i] : v1[half + i];                       \
        float k1 = up ? v1[half + i] : v1[i];                       \
        v0[i] = k0 + __shfl_xor(s0, m);                             \
        v1[i] = k1 + __shfl_xor(s1, m);                             \
    }

__global__ __launch_bounds__(256, 4)
void hfield_kernel(const float* __restrict__ x,
                   const float* __restrict__ anc,
                   float* __restrict__ out) {
    // ah[a][l][k] packs (anc[a][1+l+128k], anc[a][1+l+64+128k]) as f16x2
    __shared__ u32 ah[NA][64][4];

    const int tid = threadIdx.x, lane = tid & 63, wid = tid >> 6;

    for (int i = tid; i < NA * 256; i += 256) {
        const int a = i >> 8, rem = i & 255, l = rem >> 2, k = rem & 3;
        ah[a][l][k] = pkrtz(anc[a * DD + 1 + l + 128 * k],
                            anc[a * DD + 1 + l + 64 + 128 * k]);
    }
    __syncthreads();

    const int aidx = ((lane & 1) << 3) | (((lane >> 1) & 1) << 2) |
                     (((lane >> 2) & 1) << 1) | ((lane >> 3) & 1);

    // af0 for anchor aidx: sqrt(1 + sum(sp^2))
    float af0;
    {
        float v0[16], v1[16];
#pragma unroll
        for (int a = 0; a < NA; ++a) {
            const uint4 w = *reinterpret_cast<const uint4*>(&ah[a][lane][0]);
            float s = fdot2(w.x, w.x, 0.f);
            s = fdot2(w.y, w.y, s);
            s = fdot2(w.z, w.z, s);
            v0[a] = fdot2(w.w, w.w, s);
            v1[a] = 0.f;
        }
        RSTEP2(1, 8) RSTEP2(2, 4) RSTEP2(4, 2) RSTEP2(8, 1)
        float S = v0[0];
        S += __shfl_xor(S, 16);
        S += __shfl_xor(S, 32);
        af0 = sqrtf(1.0f + S);
    }

    const int gw = blockIdx.x * 4 + wid;
    const float* rbase = x + (size_t)gw * RPW * DD;
    float*       obase = out + (size_t)gw * RPW * DD;

    // current pair (xc0,xc1), prefetched next pair (xn0,xn1)
    float xc0[8], xc1[8], x00, x01;
    {
        const float* p0 = rbase;
        const float* p1 = rbase + DD;
#pragma unroll
        for (int j = 0; j < 8; ++j) xc0[j] = p0[1 + lane + 64 * j];
        x00 = p0[0];
#pragma unroll
        for (int j = 0; j < 8; ++j) xc1[j] = p1[1 + lane + 64 * j];
        x01 = p1[0];
    }

#pragma unroll 1
    for (int it = 0; it < RPW / 2; ++it) {
        float xn0[8] = {0,0,0,0,0,0,0,0}, xn1[8] = {0,0,0,0,0,0,0,0};
        float x0n0 = 0.f, x0n1 = 0.f;
        if (it + 1 < RPW / 2) {
            const float* p0 = rbase + (size_t)(2 * it + 2) * DD;
            const float* p1 = p0 + DD;
#pragma unroll
            for (int j = 0; j < 8; ++j) xn0[j] = p0[1 + lane + 64 * j];
            x0n0 = p0[0];
#pragma unroll
            for (int j = 0; j < 8; ++j) xn1[j] = p1[1 + lane + 64 * j];
            x0n1 = p1[0];
        }

        // pack both rows into f16 pairs along j
        const u32 a0 = pkrtz(xc0[0], xc0[1]), a1 = pkrtz(xc0[2], xc0[3]);
        const u32 a2 = pkrtz(xc0[4], xc0[5]), a3 = pkrtz(xc0[6], xc0[7]);
        const u32 b0 = pkrtz(xc1[0], xc1[1]), b1 = pkrtz(xc1[2], xc1[3]);
        const u32 b2 = pkrtz(xc1[4], xc1[5]), b3 = pkrtz(xc1[6], xc1[7]);

        float v0[16], v1[16];
#pragma unroll
        for (int a = 0; a < NA; ++a) {
            const uint4 w = *reinterpret_cast<const uint4*>(&ah[a][lane][0]);
            float s0 = fdot2(w.x, a0, 0.f);
            float s1 = fdot2(w.x, b0, 0.f);
            s0 = fdot2(w.y, a1, s0);
            s1 = fdot2(w.y, b1, s1);
            s0 = fdot2(w.z, a2, s0);
            s1 = fdot2(w.z, b2, s1);
            v0[a] = fdot2(w.w, a3, s0);
            v1[a] = fdot2(w.w, b3, s1);
        }

        RSTEP2(1, 8) RSTEP2(2, 4) RSTEP2(4, 2) RSTEP2(8, 1)
        float S0 = v0[0], S1 = v1[0];
        S0 += __shfl_xor(S0, 16);  S1 += __shfl_xor(S1, 16);
        S0 += __shfl_xor(S0, 32);  S1 += __shfl_xor(S1, 32);

        // theta for anchor aidx, clipped
        const float tc0 = fmaxf(fmaf(x00, af0, -S0), 1.0f + 1e-7f);
        const float tc1 = fmaxf(fmaf(x01, af0, -S1), 1.0f + 1e-7f);

        // packed argmin: key = (theta_bits & ~0xF) | aidx  (first-index ties)
        FU u0, u1; u0.f = tc0; u1.f = tc1;
        u32 k0 = (u0.u & 0xFFFFFFF0u) | (u32)aidx;
        u32 k1 = (u1.u & 0xFFFFFFF0u) | (u32)aidx;
#pragma unroll
        for (int m = 1; m <= 8; m <<= 1) {
            const u32 o0 = (u32)__shfl_xor((int)k0, m);
            const u32 o1 = (u32)__shfl_xor((int)k1, m);
            k0 = o0 < k0 ? o0 : k0;
            k1 = o1 < k1 ? o1 : k1;
        }
        const int bi0 = __builtin_amdgcn_readfirstlane((int)(k0 & 15u));
        const int bi1 = __builtin_amdgcn_readfirstlane((int)(k1 & 15u));

        // exact winner theta + af0 from the lane that owns that anchor
        const int ls0 = ((bi0 >> 3) & 1) | (((bi0 >> 2) & 1) << 1) |
                        (((bi0 >> 1) & 1) << 2) | ((bi0 & 1) << 3);
        const int ls1 = ((bi1 >> 3) & 1) | (((bi1 >> 2) & 1) << 1) |
                        (((bi1 >> 1) & 1) << 2) | ((bi1 & 1) << 3);
        const float t0 = __shfl(tc0, ls0);
        const float t1 = __shfl(tc1, ls1);
        const float y00 = __shfl(af0, ls0);
        const float y01 = __shfl(af0, ls1);

        // dual scalar epilogue (independent chains -> ILP)
        const float s20 = t0 * t0 - 1.0f,  s21 = t1 * t1 - 1.0f;
        const float rr0 = sqrtf(s20),      rr1 = sqrtf(s21);
        const float ac0 = __logf(t0 + rr0), ac1 = __logf(t1 + rr1);
        const float cf0 = ac0 / rr0,        cf1 = ac1 / rr1;
        const float vn0 = sqrtf(fmaxf(ALPHA * ALPHA * ac0 * ac0, EPSV));
        const float vn1 = sqrtf(fmaxf(ALPHA * ALPHA * ac1 * ac1, EPSV));
        const float e0 = __expf(vn0),  e1 = __expf(vn1);
        const float i0 = 1.0f / e0,    i1 = 1.0f / e1;
        const float ch0 = 0.5f * (e0 + i0), ch1 = 0.5f * (e1 + i1);
        const float sh0 = 0.5f * (e0 - i0), sh1 = 0.5f * (e1 - i1);
        const float c20 = ALPHA * cf0 * (sh0 / vn0);
        const float c21 = ALPHA * cf1 * (sh1 / vn1);
        const float c10 = fmaf(-c20, t0, ch0);
        const float c11 = fmaf(-c21, t1, ch1);

        // y slices for winners
        const uint4 wy0 = *reinterpret_cast<const uint4*>(&ah[bi0][lane][0]);
        const uint4 wy1 = *reinterpret_cast<const uint4*>(&ah[bi1][lane][0]);
        float yv0[8], yv1[8];
        { h2 t = asH2(wy0.x); yv0[0] = (float)t.x; yv0[1] = (float)t.y; }
        { h2 t = asH2(wy0.y); yv0[2] = (float)t.x; yv0[3] = (float)t.y; }
        { h2 t = asH2(wy0.z); yv0[4] = (float)t.x; yv0[5] = (float)t.y; }
        { h2 t = asH2(wy0.w); yv0[6] = (float)t.x; yv0[7] = (float)t.y; }
        { h2 t = asH2(wy1.x); yv1[0] = (float)t.x; yv1[1] = (float)t.y; }
        { h2 t = asH2(wy1.y); yv1[2] = (float)t.x; yv1[3] = (float)t.y; }
        { h2 t = asH2(wy1.z); yv1[4] = (float)t.x; yv1[5] = (float)t.y; }
        { h2 t = asH2(wy1.w); yv1[6] = (float)t.x; yv1[7] = (float)t.y; }

        float* op0 = obase + (size_t)(2 * it) * DD;
        float* op1 = op0 + DD;
#pragma unroll
        for (int j = 0; j < 8; ++j) {
            __builtin_nontemporal_store(fmaf(c20, yv0[j], c10 * xc0[j]),
                                        &op0[1 + lane + 64 * j]);
            __builtin_nontemporal_store(fmaf(c21, yv1[j], c11 * xc1[j]),
                                        &op1[1 + lane + 64 * j]);
        }
        if (lane == 0) {
            __builtin_nontemporal_store(fmaf(c20, y00, c10 * x00), op0);
            __builtin_nontemporal_store(fmaf(c21, y01, c11 * x01), op1);
        }

        // rotate pipeline
#pragma unroll
        for (int j = 0; j < 8; ++j) { xc0[j] = xn0[j]; xc1[j] = xn1[j]; }
        x00 = x0n0; x01 = x0n1;
    }
}

extern "C" void kernel_launch(void* const* d_in, const int* in_sizes, int n_in,
                              void* d_out, int out_size, void* d_ws, size_t ws_size,
                              hipStream_t stream) {
    const float* x   = (const float*)d_in[0];
    const float* anc = (const float*)d_in[1];
    float* out       = (float*)d_out;
    hipLaunchKernelGGL(hfield_kernel, dim3(GRID), dim3(256), 0, stream, x, anc, out);
}

// Round 7
// 139.904 us; speedup vs baseline: 1.3412x; 1.3412x over previous
//
#include <hip/hip_runtime.h>

#define NA 16
#define DD 513
#define ALPHA 0.1f
#define EPSV 1e-7f
#define TPW 2              // 16-row tiles per wave
#define GRID 1024          // 1024 blocks * 4 waves * 2 tiles * 16 rows = 131072

typedef __fp16 h2 __attribute__((ext_vector_type(2)));
typedef __fp16 f16x8 __attribute__((ext_vector_type(8)));
typedef float f32x4 __attribute__((ext_vector_type(4)));
typedef unsigned int u32;

union H2U { h2 h; u32 u; };
union FU  { float f; u32 u; int i; };
union FRAG { u32 w[4]; f16x8 v; };

static __device__ __forceinline__ u32 pkrtz(float lo, float hi) {
    H2U t; t.h = __builtin_amdgcn_cvt_pkrtz(lo, hi); return t.u;
}
static __device__ __forceinline__ h2 asH2(u32 w) { H2U t; t.u = w; return t.h; }

// 4-byte-aligned 4-float load (x rows are only 4B aligned)
struct __attribute__((packed, aligned(4))) F4 { float a, b, c, d; };

__global__ __launch_bounds__(256, 2)
void hfield_kernel(const float* __restrict__ x,
                   const float* __restrict__ anc,
                   float* __restrict__ out) {
    // y-gather layout: ah[a][l][k] = f16pair(anc[a][1+l+128k], anc[a][1+l+64+128k])
    __shared__ u32 ah[NA][64][4];
    // MFMA B-fragments: bh[kt][l][q] = f16pair of anc[l&15][1 + kt*32 + (l>>4)*8 + 2q + {0,1}]
    __shared__ u32 bh[16][64][4];
    __shared__ float parts[NA][16];
    __shared__ float af_s[NA];
    __shared__ float4 cb[4][16];      // per-wave per-row {c1, c2, y0, bi_bits}

    const int tid = threadIdx.x, lane = tid & 63, wid = tid >> 6;
    const int col = lane & 15, g = lane >> 4;

    // ---- block startup ----
    for (int i = tid; i < NA * 256; i += 256) {
        const int a = i >> 8, rem = i & 255, l = rem >> 2, k = rem & 3;
        ah[a][l][k] = pkrtz(anc[a * DD + 1 + l + 128 * k],
                            anc[a * DD + 1 + l + 64 + 128 * k]);
    }
    for (int i = tid; i < 16 * 256; i += 256) {
        const int kt = i >> 8, rem = i & 255, l = rem >> 2, q = rem & 3;
        const float* p = anc + (l & 15) * DD + 1 + kt * 32 + (l >> 4) * 8 + 2 * q;
        bh[kt][l][q] = pkrtz(p[0], p[1]);
    }
    {   // af0 partials: anchor tid>>4, segment tid&15 (32 elems)
        const int a = tid >> 4, seg = tid & 15;
        const float* p = anc + a * DD + 1 + seg * 32;
        float s = 0.f;
#pragma unroll
        for (int i = 0; i < 32; ++i) s = fmaf(p[i], p[i], s);
        parts[a][seg] = s;
    }
    __syncthreads();
    if (tid < NA) {
        float s = 0.f;
#pragma unroll
        for (int i = 0; i < 16; ++i) s += parts[tid][i];
        af_s[tid] = sqrtf(1.0f + s);
    }
    __syncthreads();

    const float af0c = af_s[col];
    const float thmin = 1.0f + 1e-7f;
    const int gw = blockIdx.x * 4 + wid;

#pragma unroll 1
    for (int t = 0; t < TPW; ++t) {
        const int rowbase = gw * (16 * TPW) + t * 16;

        // ---- MFMA phase: S[row][anchor] for 16 rows x 16 anchors, K=512 ----
        const float* arow = x + (size_t)(rowbase + col) * DD + 1 + g * 8;
        f32x4 acc = {0.f, 0.f, 0.f, 0.f};
#pragma unroll
        for (int kt = 0; kt < 16; ++kt) {
            const F4 lo = *(const F4*)(arow + kt * 32);
            const F4 hi = *(const F4*)(arow + kt * 32 + 4);
            FRAG A, Bf;
            A.w[0] = pkrtz(lo.a, lo.b); A.w[1] = pkrtz(lo.c, lo.d);
            A.w[2] = pkrtz(hi.a, hi.b); A.w[3] = pkrtz(hi.c, hi.d);
            const uint4 bw = *reinterpret_cast<const uint4*>(&bh[kt][lane][0]);
            Bf.w[0] = bw.x; Bf.w[1] = bw.y; Bf.w[2] = bw.z; Bf.w[3] = bw.w;
            acc = __builtin_amdgcn_mfma_f32_16x16x32_f16(A.v, Bf.v, acc, 0, 0, 0);
        }

        // x0 for the 4 rows this lane-group owns (row = 4g + r4)
        float x0r[4];
#pragma unroll
        for (int r4 = 0; r4 < 4; ++r4)
            x0r[r4] = x[(size_t)(rowbase + 4 * g + r4) * DD];

        // ---- theta, argmin, epilogue (4 independent chains per lane) ----
#pragma unroll
        for (int r4 = 0; r4 < 4; ++r4) {
            const float th = fmaxf(fmaf(x0r[r4], af0c, -acc[r4]), thmin);
            FU u; u.f = th;
            u32 key = (u.u & 0xFFFFFFF0u) | (u32)col;
#pragma unroll
            for (int m = 1; m <= 8; m <<= 1) {
                const u32 o = (u32)__shfl_xor((int)key, m);
                key = o < key ? o : key;
            }
            const int bi  = (int)(key & 15u);
            const int src = (lane & 48) | bi;
            const float thw = __shfl(th, src);       // exact winner theta
            const float y0  = af_s[bi];

            const float s2 = thw * thw - 1.0f;
            const float rr = sqrtf(s2);
            const float ac = __logf(thw + rr);       // arccosh
            const float cf = ac / rr;
            const float vn = sqrtf(fmaxf(ALPHA * ALPHA * ac * ac, EPSV));
            const float e  = __expf(vn);
            const float ei = 1.0f / e;
            const float ch = 0.5f * (e + ei);
            const float sh = 0.5f * (e - ei);
            const float c2 = ALPHA * cf * (sh / vn);
            const float c1 = fmaf(-c2, thw, ch);

            if (col == 0) {
                FU bf; bf.i = bi;
                cb[wid][4 * g + r4] = make_float4(c1, c2, y0, bf.f);
            }
        }
        asm volatile("s_waitcnt lgkmcnt(0)" ::: "memory");

        // ---- store phase: 16 rows, one contiguous nt stream per row ----
#pragma unroll 4
        for (int r = 0; r < 16; ++r) {
            const float4 c = cb[wid][r];
            FU bu; bu.f = c.w;
            const int bi = bu.i;
            const uint4 wy = *reinterpret_cast<const uint4*>(&ah[bi][lane][0]);
            const float* px = x + (size_t)(rowbase + r) * DD;
            float xv[8];
#pragma unroll
            for (int j = 0; j < 8; ++j) xv[j] = px[1 + lane + 64 * j];
            float yv[8];
            { h2 tt = asH2(wy.x); yv[0] = (float)tt.x; yv[1] = (float)tt.y; }
            { h2 tt = asH2(wy.y); yv[2] = (float)tt.x; yv[3] = (float)tt.y; }
            { h2 tt = asH2(wy.z); yv[4] = (float)tt.x; yv[5] = (float)tt.y; }
            { h2 tt = asH2(wy.w); yv[6] = (float)tt.x; yv[7] = (float)tt.y; }

            float* op = out + (size_t)(rowbase + r) * DD;
            const float out0 = fmaf(c.y, c.z, c.x * px[0]);
            if (lane == 0) __builtin_nontemporal_store(out0, op);
#pragma unroll
            for (int j = 0; j < 8; ++j)
                __builtin_nontemporal_store(fmaf(c.y, yv[j], c.x * xv[j]),
                                            &op[1 + lane + 64 * j]);
        }
    }
}

extern "C" void kernel_launch(void* const* d_in, const int* in_sizes, int n_in,
                              void* d_out, int out_size, void* d_ws, size_t ws_size,
                              hipStream_t stream) {
    const float* x   = (const float*)d_in[0];
    const float* anc = (const float*)d_in[1];
    float* out       = (float*)d_out;
    hipLaunchKernelGGL(hfield_kernel, dim3(GRID), dim3(256), 0, stream, x, anc, out);
}

// Round 8
// 112.125 us; speedup vs baseline: 1.6735x; 1.2477x over previous
//
#include <hip/hip_runtime.h>

#define NA 16
#define DD 513
#define ALPHA 0.1f
#define EPSV 1e-7f
#define GRID 2048   // 2048 blocks * 4 waves * 16 rows = 131072

typedef __fp16 h2v __attribute__((ext_vector_type(2)));
typedef __fp16 f16x8 __attribute__((ext_vector_type(8)));
typedef float f32x4 __attribute__((ext_vector_type(4)));
typedef unsigned int u32;

union H2U { h2v h; u32 u; };
union FU  { float f; u32 u; int i; };
union FRAG { u32 w[4]; f16x8 v; };
union U4   { uint4 v; u32 w[4]; };

static __device__ __forceinline__ u32 pkrtz(float lo, float hi) {
    H2U t; t.h = __builtin_amdgcn_cvt_pkrtz(lo, hi); return t.u;
}
static __device__ __forceinline__ h2v asH2(u32 w) { H2U t; t.u = w; return t.h; }

// Frame layout: granule G = kt*64 + l holds 4 f16-pairs for source-row (l&15),
// k-slot l' = 4*kt + (l>>4); pair q = (d-1 = l'+128q, d-1 = l'+64+128q).
// XOR-swizzle keeps all four access patterns (stage-write, mfma-read,
// store-read, y-gather) conflict-free.
static __device__ __forceinline__ int swz(int G) {
    return G ^ (((G >> 4) & 3) | (((G >> 6) & 1) << 2));
}

__global__ __launch_bounds__(256, 2)
void hfield_kernel(const float* __restrict__ x,
                   const float* __restrict__ anc,
                   float* __restrict__ out) {
    __shared__ uint4 bframe[1024];        // anchors, 16 KB (block-wide)
    __shared__ uint4 xframe[4][1024];     // x tile, 16 KB per wave

    const int tid = threadIdx.x, lane = tid & 63, wid = tid >> 6;
    const int col = lane & 15, g = lane >> 4;

    // ---- stage anchors into bframe ----
#pragma unroll
    for (int m = 0; m < 4; ++m) {
        const int F = m * 256 + tid;
        const int l = F & 63, kt = F >> 6;
        const int a = l & 15, lp = 4 * kt + (l >> 4);
        const float* p = anc + a * DD + 1 + lp;
        uint4 w;
        w.x = pkrtz(p[0],   p[64]);
        w.y = pkrtz(p[128], p[192]);
        w.z = pkrtz(p[256], p[320]);
        w.w = pkrtz(p[384], p[448]);
        bframe[swz(F)] = w;
    }

    // ---- af0 for anchor `col` (segment-parallel over g, fold) ----
    float af0c;
    {
        const float* p = anc + col * DD + 1 + g * 128;
        float s = 0.f;
#pragma unroll 16
        for (int i = 0; i < 128; ++i) s = fmaf(p[i], p[i], s);
        s += __shfl_xor(s, 16);
        s += __shfl_xor(s, 32);
        af0c = sqrtf(1.0f + s);
    }
    __syncthreads();

    const int rowbase = (blockIdx.x * 4 + wid) * 16;
    uint4* xf = xframe[wid];
    const float* xb = x + (size_t)rowbase * DD;

    // x0 for the 4 rows this lane's group owns (C-layout row = 4g + r4)
    float x0r[4];
#pragma unroll
    for (int r4 = 0; r4 < 4; ++r4) x0r[r4] = xb[(size_t)(4 * g + r4) * DD];

    // ---- stage x tile (read x ONCE, coalesced) ----
#pragma unroll 8
    for (int r = 0; r < 16; ++r) {
        const float* p = xb + (size_t)r * DD + 1 + lane;
        float v[8];
#pragma unroll
        for (int j = 0; j < 8; ++j) v[j] = p[64 * j];
        uint4 w;
        w.x = pkrtz(v[0], v[1]);
        w.y = pkrtz(v[2], v[3]);
        w.z = pkrtz(v[4], v[5]);
        w.w = pkrtz(v[6], v[7]);
        xf[swz((lane >> 2) * 64 + 16 * (lane & 3) + r)] = w;
    }
    asm volatile("s_waitcnt lgkmcnt(0)" ::: "memory");

    // ---- MFMA: S[row][anchor], 16 rows x 16 anchors, K=512 ----
    f32x4 acc = {0.f, 0.f, 0.f, 0.f};
#pragma unroll
    for (int kt = 0; kt < 16; ++kt) {
        FRAG A, B;
        U4 ax, bx;
        ax.v = xf[swz(kt * 64 + lane)];
        bx.v = bframe[swz(kt * 64 + lane)];
        A.w[0] = ax.w[0]; A.w[1] = ax.w[1]; A.w[2] = ax.w[2]; A.w[3] = ax.w[3];
        B.w[0] = bx.w[0]; B.w[1] = bx.w[1]; B.w[2] = bx.w[2]; B.w[3] = bx.w[3];
        acc = __builtin_amdgcn_mfma_f32_16x16x32_f16(A.v, B.v, acc, 0, 0, 0);
    }

    // ---- theta, argmin, epilogue: 4 independent chains per lane ----
    const float thmin = 1.0f + 1e-7f;
    float c1r[4], c2r[4], o0r[4];
    int bir[4];
#pragma unroll
    for (int r4 = 0; r4 < 4; ++r4) {
        const float th = fmaxf(fmaf(x0r[r4], af0c, -acc[r4]), thmin);
        FU u; u.f = th;
        u32 key = (u.u & 0xFFFFFFF0u) | (u32)col;
#pragma unroll
        for (int m = 1; m <= 8; m <<= 1) {
            const u32 o = (u32)__shfl_xor((int)key, m);
            key = o < key ? o : key;
        }
        const int bi  = (int)(key & 15u);
        const int src = (lane & 48) | bi;
        const float thw = __shfl(th, src);     // exact winner theta
        const float y0  = __shfl(af0c, src);   // winner af0

        const float s2 = thw * thw - 1.0f;
        const float rr = sqrtf(s2);
        const float ac = __logf(thw + rr);     // arccosh
        const float cf = ac / rr;
        const float vn = sqrtf(fmaxf(ALPHA * ALPHA * ac * ac, EPSV));
        const float e  = __expf(vn);
        const float ei = 1.0f / e;
        const float ch = 0.5f * (e + ei);
        const float sh = 0.5f * (e - ei);
        const float c2 = ALPHA * cf * (sh / vn);
        const float c1 = fmaf(-c2, thw, ch);

        c1r[r4] = c1;
        c2r[r4] = c2;
        o0r[r4] = fmaf(c2, y0, c1 * x0r[r4]);
        bir[r4] = bi;
    }

    // ---- store phase: 16 rows, sequential contiguous nt streams ----
#pragma unroll 4
    for (int r = 0; r < 16; ++r) {
        const int src = (r >> 2) * 16;                   // producer group
        const float c1 = __shfl(c1r[r & 3], src);
        const float c2 = __shfl(c2r[r & 3], src);
        const float o0 = __shfl(o0r[r & 3], src);
        const int   bi = __builtin_amdgcn_readfirstlane(__shfl(bir[r & 3], src));

        U4 X, Y;
        X.v = xf[swz((lane >> 2) * 64 + 16 * (lane & 3) + r)];
        Y.v = bframe[swz((lane >> 2) * 64 + 16 * (lane & 3) + bi)];

        float* op = out + (size_t)(rowbase + r) * DD;
        if (lane == 0) __builtin_nontemporal_store(o0, op);
#pragma unroll
        for (int q = 0; q < 4; ++q) {
            const h2v hx = asH2(X.w[q]);
            const h2v hy = asH2(Y.w[q]);
            __builtin_nontemporal_store(fmaf(c2, (float)hy.x, c1 * (float)hx.x),
                                        &op[1 + lane + 128 * q]);
            __builtin_nontemporal_store(fmaf(c2, (float)hy.y, c1 * (float)hx.y),
                                        &op[1 + lane + 64 + 128 * q]);
        }
    }
}

extern "C" void kernel_launch(void* const* d_in, const int* in_sizes, int n_in,
                              void* d_out, int out_size, void* d_ws, size_t ws_size,
                              hipStream_t stream) {
    const float* x   = (const float*)d_in[0];
    const float* anc = (const float*)d_in[1];
    float* out       = (float*)d_out;
    hipLaunchKernelGGL(hfield_kernel, dim3(GRID), dim3(256), 0, stream, x, anc, out);
}